// Round 14
// baseline (569.569 us; speedup 1.0000x reference)
//
#include <hip/hip_runtime.h>

// Problem constants
constexpr int NN  = 131072;   // nodes
constexpr int NE  = 2097152;  // edges
constexpr int HD  = 128;      // hidden
constexpr int NG  = 8192;     // graphs
constexpr int NA  = 28;       // atom types
constexpr int NL  = 4;        // layers

// CSR bucketing
constexpr int NB   = 256;     // buckets
constexpr int BSH  = 9;       // dst>>9 -> bucket (512 nodes/bucket)
constexpr int BNOD = 512;     // nodes per bucket
constexpr int CAP  = 10240;   // slots per bucket (mean 8192 + 22 sigma)

// ---------------- workspace layout (bytes) ----------------
constexpr size_t SZ_FB   = (size_t)NN * HD * 2;          // 32 MiB bf16 feature buf
constexpr size_t OFF_XB   = 0;
constexpr size_t OFF_YB   = OFF_XB + SZ_FB;
constexpr size_t OFF_PB   = OFF_YB + SZ_FB;              // P = H @ W2, fp8 e4m3 (16 MiB)
constexpr size_t OFF_ESRC = OFF_PB + SZ_FB;
constexpr size_t OFF_DEG  = OFF_ESRC + (size_t)NE * 4;
constexpr size_t OFF_GCNT = OFF_DEG + (size_t)NN * 4;
constexpr size_t OFF_ROW  = OFF_GCNT + (size_t)NG * 4;
constexpr size_t OFF_IDEG = OFF_ROW + (size_t)NN * 4;
constexpr size_t OFF_IGC  = OFF_IDEG + (size_t)NN * 4;
constexpr size_t OFF_WC   = OFF_IGC + (size_t)NG * 4;
constexpr size_t OFF_WNT  = OFF_WC + 512;                // bf16 W transposed [L][128][256]
constexpr size_t OFF_EBUF = OFF_WNT + (size_t)NL * HD * 256 * 2;
constexpr size_t OFF_GCUR = OFF_EBUF + (size_t)NB * CAP * 4;
constexpr size_t OFF_WET  = OFF_GCUR + (size_t)NB * 4;   // bf16 W_emb^T [128][32]

// ---------------- bf16 / fp8 helpers ----------------
__device__ __forceinline__ float blo(uint x) { return __uint_as_float(x << 16); }
__device__ __forceinline__ float bhi(uint x) { return __uint_as_float(x & 0xFFFF0000u); }
__device__ __forceinline__ unsigned short f2b(float f) {
  uint u = __float_as_uint(f);
  return (unsigned short)((u + 0x7FFFu + ((u >> 16) & 1u)) >> 16);
}
__device__ __forceinline__ uint pack2(float a, float b) {
  uint ua = __float_as_uint(a), ub = __float_as_uint(b);
  uint lo = (ua + 0x7FFFu + ((ua >> 16) & 1u)) >> 16;
  uint hi = (ub + 0x7FFFu + ((ub >> 16) & 1u)) & 0xFFFF0000u;
  return lo | hi;
}

typedef __attribute__((ext_vector_type(8))) short bf16x8;
typedef __attribute__((ext_vector_type(4))) float f32x4;
typedef __attribute__((ext_vector_type(2))) float f32x2;

// pack 4 f32 -> 4 fp8 e4m3 in one uint (2 HW instrs)
__device__ __forceinline__ uint pk_fp8x4(float a, float b, float c, float d) {
  int p = __builtin_amdgcn_cvt_pk_fp8_f32(a, b, 0, false);
  p = __builtin_amdgcn_cvt_pk_fp8_f32(c, d, p, true);
  return (uint)p;
}

// ---------------- graph-id histogram (needs zeroed gcnt) ----------------
__global__ void k_ghist(const int* __restrict__ gid, int* __restrict__ gcnt) {
  int i = blockIdx.x * blockDim.x + threadIdx.x;
  if (i < NN) atomicAdd(&gcnt[gid[i]], 1);
}

// ---------------- fused setup: gcur init / ginit / wprep / weprep / wcombo ----
__global__ void k_prep(int* __restrict__ gcur, const int* __restrict__ gcnt,
                       float* __restrict__ inv_gcnt, float* __restrict__ out,
                       const float* __restrict__ b_pred,
                       const float* __restrict__ Wn, unsigned short* __restrict__ Wnt,
                       const float* __restrict__ We, unsigned short* __restrict__ Wet,
                       const float* __restrict__ W_ro, const float* __restrict__ W_pred,
                       float* __restrict__ wcv) {
  int bi = blockIdx.x, t = threadIdx.x;
  if (bi == 0) {
    gcur[t] = t * CAP;
  } else if (bi < 1 + NG / 256) {
    int g = (bi - 1) * 256 + t;
    inv_gcnt[g] = 1.0f / fmaxf((float)gcnt[g], 1.0f);
    out[g] = b_pred[0];
  } else if (bi < 1 + NG / 256 + 512) {
    int i = (bi - 1 - NG / 256) * 256 + t;        // L*256*128 total
    int l = i >> 15, k = (i >> 7) & 255, c = i & 127;
    Wnt[((size_t)l * HD + c) * 256 + k] = f2b(Wn[((size_t)l * 256 + k) * HD + c]);
  } else if (bi < 1 + NG / 256 + 512 + 16) {
    int i = (bi - 1 - NG / 256 - 512) * 256 + t;  // 128*32 total
    int col = i >> 5, k = i & 31;
    Wet[i] = (k < NA) ? f2b(We[(size_t)k * HD + col]) : (unsigned short)0;
  } else {
    if (t < 128) {
      float a = 0.f;
      for (int j = 0; j < HD; j++) a += W_ro[t * HD + j] * W_pred[j];
      wcv[t] = a;
    }
  }
}

// ---------------- bin edges into NB buckets by dst>>BSH ----------------
// packed = (dst&511)<<17 | src
__global__ __launch_bounds__(256) void k_bin(const int* __restrict__ src,
                                             const int* __restrict__ dst,
                                             int* __restrict__ gcur,
                                             uint* __restrict__ ebuf) {
  __shared__ int cnt[NB];
  __shared__ int gbase[NB];
  int t = threadIdx.x;
  cnt[t] = 0;
  int es[16], ed[16];
  int base = blockIdx.x * 4096 + t;
#pragma unroll
  for (int j = 0; j < 16; j++) {
    es[j] = src[base + j * 256];
    ed[j] = dst[base + j * 256];
  }
  __syncthreads();
#pragma unroll
  for (int j = 0; j < 16; j++) atomicAdd(&cnt[ed[j] >> BSH], 1);
  __syncthreads();
  int c = cnt[t];
  if (c > 0) gbase[t] = atomicAdd(&gcur[t], c);
  cnt[t] = 0;
  __syncthreads();
#pragma unroll
  for (int j = 0; j < 16; j++) {
    int b = ed[j] >> BSH;
    int r = atomicAdd(&cnt[b], 1);
    ebuf[(size_t)gbase[b] + r] = ((uint)(ed[j] & (BNOD - 1)) << 17) | (uint)es[j];
  }
}

// ---------------- fused CSR: hist + scans + row_start/deg/inv_deg + place ------
__global__ __launch_bounds__(256) void k_csr(const int* __restrict__ gcur,
                                             const uint* __restrict__ ebuf,
                                             int* __restrict__ deg,
                                             int* __restrict__ row_start,
                                             float* __restrict__ inv_deg,
                                             int* __restrict__ esrc) {
  __shared__ int h[BNOD];      // histogram, later cursors
  __shared__ int ps[NB];       // pair-sum scan
  __shared__ int bs[NB];       // bucket-size scan
  int b = blockIdx.x, t = threadIdx.x;

  bs[t] = gcur[t] - t * CAP;   // bucket sizes
  h[t] = 0; h[t + 256] = 0;
  __syncthreads();
  for (int o = 1; o < 256; o <<= 1) {         // inclusive scan of bucket sizes
    int v = (t >= o) ? bs[t - o] : 0;
    __syncthreads();
    bs[t] += v;
    __syncthreads();
  }
  int boff = (b == 0) ? 0 : bs[b - 1];
  int n = gcur[b] - b * CAP;

  const uint* eb = ebuf + (size_t)b * CAP;
  for (int i = t; i < n; i += 256) atomicAdd(&h[eb[i] >> 17], 1);
  __syncthreads();

  int d0 = h[2 * t], d1 = h[2 * t + 1];
  ps[t] = d0 + d1;
  __syncthreads();
  for (int o = 1; o < 256; o <<= 1) {         // inclusive scan of node pairs
    int v = (t >= o) ? ps[t - o] : 0;
    __syncthreads();
    ps[t] += v;
    __syncthreads();
  }
  int excl = ps[t] - (d0 + d1);
  int r0 = boff + excl, r1 = r0 + d0;
  int v0 = b * BNOD + 2 * t;
  deg[v0] = d0;  deg[v0 + 1] = d1;
  row_start[v0] = r0;  row_start[v0 + 1] = r1;
  inv_deg[v0]     = 1.0f / fmaxf((float)d0, 1.0f);
  inv_deg[v0 + 1] = 1.0f / fmaxf((float)d1, 1.0f);
  __syncthreads();
  h[2 * t] = r0;  h[2 * t + 1] = r1;          // cursors
  __syncthreads();
  for (int i = t; i < n; i += 256) {
    uint p = eb[i];
    int r = atomicAdd(&h[p >> 17], 1);
    esrc[r] = (int)(p & 0x1FFFFu);
  }
}

// ---------------- embedding (MFMA): Xb = bf16(h @ W_emb) ----------------
__global__ __launch_bounds__(256) void k_embed(const float* __restrict__ h,
                                               const unsigned short* __restrict__ Wet,
                                               unsigned short* __restrict__ Xb) {
  int t = threadIdx.x;
  int lane = t & 63, w = t >> 6;
  int wr = w >> 1, wc = w & 1;
  int row0 = blockIdx.x * 64 + wr * 32;
  int col0 = wc * 64;
  int fr = lane & 15;
  int fk = (lane >> 4) * 8;

  f32x4 acc[2][4] = {};
  bf16x8 a[2];
#pragma unroll
  for (int rt = 0; rt < 2; rt++) {
    int row = row0 + rt * 16 + fr;
    const float* hp = h + (size_t)row * NA + fk;
    float4 p = *(const float4*)hp;                    // k = fk..fk+3 (always < 28)
    float4 q = make_float4(0.f, 0.f, 0.f, 0.f);
    if (fk < 24) q = *(const float4*)(hp + 4);        // k = fk+4..fk+7; fk==24 -> pad 0
    a[rt][0] = (short)f2b(p.x); a[rt][1] = (short)f2b(p.y);
    a[rt][2] = (short)f2b(p.z); a[rt][3] = (short)f2b(p.w);
    a[rt][4] = (short)f2b(q.x); a[rt][5] = (short)f2b(q.y);
    a[rt][6] = (short)f2b(q.z); a[rt][7] = (short)f2b(q.w);
  }
#pragma unroll
  for (int ct = 0; ct < 4; ct++) {
    int col = col0 + ct * 16 + fr;
    bf16x8 b = *(const bf16x8*)(Wet + (size_t)col * 32 + fk);
#pragma unroll
    for (int rt = 0; rt < 2; rt++)
      acc[rt][ct] = __builtin_amdgcn_mfma_f32_16x16x32_bf16(a[rt], b, acc[rt][ct], 0, 0, 0);
  }
  int oc = lane & 15, orb = (lane >> 4) * 4;
#pragma unroll
  for (int rt = 0; rt < 2; rt++) {
#pragma unroll
    for (int ct = 0; ct < 4; ct++) {
      int col = col0 + ct * 16 + oc;
#pragma unroll
      for (int r = 0; r < 4; r++) {
        int row = row0 + rt * 16 + orb + r;
        Xb[(size_t)row * HD + col] = f2b(acc[rt][ct][r]);
      }
    }
  }
}

// ---------------- dual GEMM (MFMA, swapped operands): ----------------
// Qb = bf16(Hb @ W1 + bias), Pb8 = fp8(Hb @ W2); W = [W1; W2] (256 x 128).
__global__ __launch_bounds__(256) void k_pq(const unsigned short* __restrict__ Hb,
                                            uint* __restrict__ Pb8,
                                            unsigned short* __restrict__ Qb,
                                            const unsigned short* __restrict__ Wt,
                                            const float* __restrict__ bias) {
  int t = threadIdx.x;
  int lane = t & 63, w = t >> 6;
  int ng = w >> 1, cg = w & 1;
  int fr = lane & 15, fkg = lane >> 4;
  int n0 = blockIdx.x * 64 + ng * 32;

  f32x4 accQ[2][4] = {}, accP[2][4] = {};
#pragma unroll
  for (int ks = 0; ks < 4; ks++) {
    bf16x8 aH[2];
#pragma unroll
    for (int nt = 0; nt < 2; nt++)
      aH[nt] = *(const bf16x8*)(Hb + (size_t)(n0 + nt * 16 + fr) * HD + ks * 32 + fkg * 8);
#pragma unroll
    for (int ct = 0; ct < 4; ct++) {
      const unsigned short* wrow =
          Wt + (size_t)(cg * 64 + ct * 16 + fr) * 256 + ks * 32 + fkg * 8;
      bf16x8 b1 = *(const bf16x8*)wrow;           // W1: k in [0,128)
      bf16x8 b2 = *(const bf16x8*)(wrow + 128);   // W2: k in [128,256)
#pragma unroll
      for (int nt = 0; nt < 2; nt++) {
        accQ[nt][ct] = __builtin_amdgcn_mfma_f32_16x16x32_bf16(b1, aH[nt], accQ[nt][ct], 0, 0, 0);
        accP[nt][ct] = __builtin_amdgcn_mfma_f32_16x16x32_bf16(b2, aH[nt], accP[nt][ct], 0, 0, 0);
      }
    }
  }
  // epilogue: lane -> node = n0+nt*16+fr, channels c0..c0+3
#pragma unroll
  for (int nt = 0; nt < 2; nt++) {
    int node = n0 + nt * 16 + fr;
#pragma unroll
    for (int ct = 0; ct < 4; ct++) {
      int c0 = cg * 64 + ct * 16 + fkg * 4;
      float4 bv = *(const float4*)(bias + c0);
      uint2 q;
      q.x = pack2(accQ[nt][ct][0] + bv.x, accQ[nt][ct][1] + bv.y);
      q.y = pack2(accQ[nt][ct][2] + bv.z, accQ[nt][ct][3] + bv.w);
      *(uint2*)(Qb + (size_t)node * HD + c0) = q;
      Pb8[(size_t)node * 32 + (c0 >> 2)] =
          pk_fp8x4(accP[nt][ct][0], accP[nt][ct][1], accP[nt][ct][2], accP[nt][ct][3]);
    }
  }
}

// ---------------- gather (fp8 P) + layer epilogue, v5: 2 nodes/wave ----------
// wave owns nodes (va, vb). lane = (eg = lane>>4: edge slot, cl = lane&15).
// Index preload: lanes 0..31 -> va's first 32 edges, 32..63 -> vb's.
// Each 16-edge batch issues 8 loads (4 per node) = 32 cache lines in flight.
// Epilogue split: eg==0 lanes finish va, eg==1 lanes finish vb.
__global__ __launch_bounds__(256, 4) void k_gapply(const uint2* __restrict__ Pg,
                      const uint4* __restrict__ Qg, const uint4* __restrict__ Hres,
                      uint4* __restrict__ Og,
                      const int* __restrict__ row_start, const int* __restrict__ deg,
                      const int* __restrict__ esrc, const float* __restrict__ inv_deg,
                      const float* __restrict__ snorm,
                      const float* __restrict__ wcv, const int* __restrict__ gid,
                      const float* __restrict__ inv_gcnt, float* __restrict__ out,
                      int last) {
  int w = threadIdx.x >> 6;
  int lane = threadIdx.x & 63;
  int va = blockIdx.x * 8 + w * 2;
  int vb = va + 1;
  int eg = lane >> 4;                       // edge slot 0..3
  int cl = lane & 15;                       // uint2 col: fp8 cols 8cl..8cl+7

  int rsa = __builtin_amdgcn_readfirstlane(row_start[va]);
  int da  = __builtin_amdgcn_readfirstlane(deg[va]);
  int rsb = __builtin_amdgcn_readfirstlane(row_start[vb]);
  int db  = __builtin_amdgcn_readfirstlane(deg[vb]);

  // ---- hoisted epilogue operands (latency hides under the gather) ----
  float ida = inv_deg[va], idb = inv_deg[vb];
  float sna = snorm[va],  snb = snorm[vb];
  uint4 qa  = Qg[(size_t)va * 16 + cl];
  uint4 qb  = Qg[(size_t)vb * 16 + cl];
  uint4 hra = Hres[(size_t)va * 16 + cl];
  uint4 hrb = Hres[(size_t)vb * 16 + cl];

  // ---- index preload: half-wave per node, up to 32 edges each ----
  int half = lane >> 5, l32 = lane & 31;
  int dxa = min(da, 32), dxb = min(db, 32);
  int rsx = half ? rsb : rsa;
  int dxx = half ? dxb : dxa;
  int myidx = 0;
  if (l32 < dxx) myidx = esrc[rsx + l32];

  float Aa[8] = {}, Ab[8] = {};

#define ACC8(ACC, X)                                                        \
  { f32x2 p0 = __builtin_amdgcn_cvt_pk_f32_fp8((int)(X).x, false);          \
    f32x2 p1 = __builtin_amdgcn_cvt_pk_f32_fp8((int)(X).x, true);           \
    f32x2 p2 = __builtin_amdgcn_cvt_pk_f32_fp8((int)(X).y, false);          \
    f32x2 p3 = __builtin_amdgcn_cvt_pk_f32_fp8((int)(X).y, true);           \
    ACC[0] += p0[0]; ACC[1] += p0[1]; ACC[2] += p1[0]; ACC[3] += p1[1];     \
    ACC[4] += p2[0]; ACC[5] += p2[1]; ACC[6] += p3[0]; ACC[7] += p3[1]; }

  int dmax = max(dxa, dxb);
  for (int e = 0; e < dmax; e += 16) {      // e in {0, 16}
    uint2 xa[4], xb[4];
#pragma unroll
    for (int j = 0; j < 4; j++) {
      xa[j] = make_uint2(0u, 0u);
      int ia = __shfl(myidx, e + 4 * j + eg, 64);            // lanes 0..31
      if (e + 4 * j + eg < dxa) xa[j] = Pg[(size_t)ia * 16 + cl];
    }
#pragma unroll
    for (int j = 0; j < 4; j++) {
      xb[j] = make_uint2(0u, 0u);
      int ib = __shfl(myidx, 32 + e + 4 * j + eg, 64);       // lanes 32..63
      if (e + 4 * j + eg < dxb) xb[j] = Pg[(size_t)ib * 16 + cl];
    }
#pragma unroll
    for (int j = 0; j < 4; j++) ACC8(Aa, xa[j])
#pragma unroll
    for (int j = 0; j < 4; j++) ACC8(Ab, xb[j])
  }
  // d > 32 overflow (essentially never at Poisson(16))
  for (int ee = 32; ee < da; ee += 4) {
    uint2 x = make_uint2(0u, 0u);
    if (ee + eg < da) x = Pg[(size_t)esrc[rsa + ee + eg] * 16 + cl];
    ACC8(Aa, x)
  }
  for (int ee = 32; ee < db; ee += 4) {
    uint2 x = make_uint2(0u, 0u);
    if (ee + eg < db) x = Pg[(size_t)esrc[rsb + ee + eg] * 16 + cl];
    ACC8(Ab, x)
  }
#undef ACC8

  // reduce across the 4 edge slots (both nodes)
#pragma unroll
  for (int i = 0; i < 8; i++) {
    Aa[i] += __shfl_xor(Aa[i], 16, 64);
    Aa[i] += __shfl_xor(Aa[i], 32, 64);
    Ab[i] += __shfl_xor(Ab[i], 16, 64);
    Ab[i] += __shfl_xor(Ab[i], 32, 64);
  }

  if (eg < 2) {                             // eg==0: va, eg==1: vb
    bool isA = (eg == 0);
    int v    = isA ? va : vb;
    float id = isA ? ida : idb;
    float sn = isA ? sna : snb;
    uint4 q  = isA ? qa : qb;
    uint4 hr = isA ? hra : hrb;
    float s0 = isA ? Aa[0] : Ab[0];
    float s1 = isA ? Aa[1] : Ab[1];
    float s2 = isA ? Aa[2] : Ab[2];
    float s3 = isA ? Aa[3] : Ab[3];
    float s4 = isA ? Aa[4] : Ab[4];
    float s5 = isA ? Aa[5] : Ab[5];
    float s6 = isA ? Aa[6] : Ab[6];
    float s7 = isA ? Aa[7] : Ab[7];
    float o0 = fmaxf(blo(q.x) + s0 * id, 0.f) * sn + blo(hr.x);
    float o1 = fmaxf(bhi(q.x) + s1 * id, 0.f) * sn + bhi(hr.x);
    float o2 = fmaxf(blo(q.y) + s2 * id, 0.f) * sn + blo(hr.y);
    float o3 = fmaxf(bhi(q.y) + s3 * id, 0.f) * sn + bhi(hr.y);
    float o4 = fmaxf(blo(q.z) + s4 * id, 0.f) * sn + blo(hr.z);
    float o5 = fmaxf(bhi(q.z) + s5 * id, 0.f) * sn + bhi(hr.z);
    float o6 = fmaxf(blo(q.w) + s6 * id, 0.f) * sn + blo(hr.w);
    float o7 = fmaxf(bhi(q.w) + s7 * id, 0.f) * sn + bhi(hr.w);
    if (!last) {
      uint4 o;
      o.x = pack2(o0, o1);
      o.y = pack2(o2, o3);
      o.z = pack2(o4, o5);
      o.w = pack2(o6, o7);
      Og[(size_t)v * 16 + cl] = o;
    } else {
      float4 w0 = *(const float4*)(wcv + 8 * cl);
      float4 w1 = *(const float4*)(wcv + 8 * cl + 4);
      float p = o0 * w0.x + o1 * w0.y + o2 * w0.z + o3 * w0.w
              + o4 * w1.x + o5 * w1.y + o6 * w1.z + o7 * w1.w;
      p += __shfl_xor(p, 8, 64);            // xor<16 stays within each 16-lane group
      p += __shfl_xor(p, 4, 64);
      p += __shfl_xor(p, 2, 64);
      p += __shfl_xor(p, 1, 64);
      if (cl == 0) {
        int g = gid[v];
        atomicAdd(&out[g], p * inv_gcnt[g]);
      }
    }
  }
}

// ---------------- launch ----------------
extern "C" void kernel_launch(void* const* d_in, const int* in_sizes, int n_in,
                              void* d_out, int out_size, void* d_ws, size_t ws_size,
                              hipStream_t stream) {
  const float* h      = (const float*)d_in[0];
  const float* snorm  = (const float*)d_in[1];
  const float* W_emb  = (const float*)d_in[2];
  const float* W_node = (const float*)d_in[3];
  const float* b_node = (const float*)d_in[4];
  const float* W_ro   = (const float*)d_in[5];
  const float* W_pred = (const float*)d_in[6];
  const float* b_pred = (const float*)d_in[7];
  const int*   src    = (const int*)d_in[8];
  const int*   dst    = (const int*)d_in[9];
  const int*   gid    = (const int*)d_in[10];
  float* out = (float*)d_out;

  char* ws = (char*)d_ws;
  unsigned short* Xb   = (unsigned short*)(ws + OFF_XB);
  unsigned short* Yb   = (unsigned short*)(ws + OFF_YB);
  uint*  Pb8      = (uint*)(ws + OFF_PB);
  int*   esrc     = (int*)(ws + OFF_ESRC);
  int*   deg      = (int*)(ws + OFF_DEG);
  int*   gcnt     = (int*)(ws + OFF_GCNT);
  int*   row_s    = (int*)(ws + OFF_ROW);
  float* inv_deg  = (float*)(ws + OFF_IDEG);
  float* inv_gcnt = (float*)(ws + OFF_IGC);
  float* wcv      = (float*)(ws + OFF_WC);
  unsigned short* Wnt = (unsigned short*)(ws + OFF_WNT);
  uint*  ebuf     = (uint*)(ws + OFF_EBUF);
  int*   gcur     = (int*)(ws + OFF_GCUR);
  unsigned short* Wet = (unsigned short*)(ws + OFF_WET);

  hipMemsetAsync(ws + OFF_GCNT, 0, (size_t)NG * 4, stream);

  k_ghist<<<NN / 256, 256, 0, stream>>>(gid, gcnt);
  k_prep<<<1 + NG / 256 + 512 + 16 + 1, 256, 0, stream>>>(
      gcur, gcnt, inv_gcnt, out, b_pred, W_node, Wnt, W_emb, Wet, W_ro, W_pred, wcv);
  k_bin<<<NE / 4096, 256, 0, stream>>>(src, dst, gcur, ebuf);
  k_csr<<<NB, 256, 0, stream>>>(gcur, ebuf, deg, row_s, inv_deg, esrc);

  k_embed<<<NN / 64, 256, 0, stream>>>(h, Wet, Xb);

  for (int l = 0; l < NL; l++) {
    unsigned short* hb = (l & 1) ? Yb : Xb;   // layer input
    unsigned short* qo = (l & 1) ? Xb : Yb;   // Q buffer, overwritten in-place by O
    k_pq<<<NN / 64, 256, 0, stream>>>(hb, Pb8, qo, Wnt + (size_t)l * HD * 256,
                                      b_node + (size_t)l * HD);
    k_gapply<<<NN / 8, 256, 0, stream>>>((const uint2*)Pb8, (const uint4*)qo,
                                         (const uint4*)hb, (uint4*)qo,
                                         row_s, deg, esrc, inv_deg, snorm,
                                         wcv, gid, inv_gcnt, out, (l == NL - 1) ? 1 : 0);
  }
}

// Round 15
// 538.990 us; speedup vs baseline: 1.0567x; 1.0567x over previous
//
#include <hip/hip_runtime.h>

// Problem constants
constexpr int NN  = 131072;   // nodes
constexpr int NE  = 2097152;  // edges
constexpr int HD  = 128;      // hidden
constexpr int NG  = 8192;     // graphs
constexpr int NA  = 28;       // atom types
constexpr int NL  = 4;        // layers

// CSR bucketing
constexpr int NB   = 256;     // buckets
constexpr int BSH  = 9;       // dst>>9 -> bucket (512 nodes/bucket)
constexpr int BNOD = 512;     // nodes per bucket
constexpr int CAP  = 10240;   // slots per bucket (mean 8192 + 22 sigma)

// ---------------- workspace layout (bytes) ----------------
constexpr size_t SZ_FB   = (size_t)NN * HD * 2;          // 32 MiB bf16 feature buf
constexpr size_t OFF_XB   = 0;
constexpr size_t OFF_YB   = OFF_XB + SZ_FB;
constexpr size_t OFF_PB   = OFF_YB + SZ_FB;              // P = H @ W2, fp8 e4m3 (16 MiB)
constexpr size_t OFF_ESRC = OFF_PB + SZ_FB;
constexpr size_t OFF_DEG  = OFF_ESRC + (size_t)NE * 4;
constexpr size_t OFF_GCNT = OFF_DEG + (size_t)NN * 4;
constexpr size_t OFF_ROW  = OFF_GCNT + (size_t)NG * 4;
constexpr size_t OFF_IDEG = OFF_ROW + (size_t)NN * 4;
constexpr size_t OFF_IGC  = OFF_IDEG + (size_t)NN * 4;
constexpr size_t OFF_WC   = OFF_IGC + (size_t)NG * 4;
constexpr size_t OFF_WNT  = OFF_WC + 512;                // bf16 W transposed [L][128][256]
constexpr size_t OFF_EBUF = OFF_WNT + (size_t)NL * HD * 256 * 2;
constexpr size_t OFF_GCUR = OFF_EBUF + (size_t)NB * CAP * 4;
constexpr size_t OFF_WET  = OFF_GCUR + (size_t)NB * 4;   // bf16 W_emb^T [128][32]

// ---------------- bf16 / fp8 helpers ----------------
__device__ __forceinline__ float blo(uint x) { return __uint_as_float(x << 16); }
__device__ __forceinline__ float bhi(uint x) { return __uint_as_float(x & 0xFFFF0000u); }
__device__ __forceinline__ unsigned short f2b(float f) {
  uint u = __float_as_uint(f);
  return (unsigned short)((u + 0x7FFFu + ((u >> 16) & 1u)) >> 16);
}
__device__ __forceinline__ uint pack2(float a, float b) {
  uint ua = __float_as_uint(a), ub = __float_as_uint(b);
  uint lo = (ua + 0x7FFFu + ((ua >> 16) & 1u)) >> 16;
  uint hi = (ub + 0x7FFFu + ((ub >> 16) & 1u)) & 0xFFFF0000u;
  return lo | hi;
}

typedef __attribute__((ext_vector_type(8))) short bf16x8;
typedef __attribute__((ext_vector_type(4))) float f32x4;
typedef __attribute__((ext_vector_type(2))) float f32x2;

// pack 4 f32 -> 4 fp8 e4m3 in one uint (2 HW instrs)
__device__ __forceinline__ uint pk_fp8x4(float a, float b, float c, float d) {
  int p = __builtin_amdgcn_cvt_pk_fp8_f32(a, b, 0, false);
  p = __builtin_amdgcn_cvt_pk_fp8_f32(c, d, p, true);
  return (uint)p;
}

// ---------------- graph-id histogram (needs zeroed gcnt) ----------------
__global__ void k_ghist(const int* __restrict__ gid, int* __restrict__ gcnt) {
  int i = blockIdx.x * blockDim.x + threadIdx.x;
  if (i < NN) atomicAdd(&gcnt[gid[i]], 1);
}

// ---------------- fused setup: gcur init / ginit / wprep / weprep / wcombo ----
// grid = 1 + NG/256 + 512 + 16 + 1 = 562 blocks, branch by block range.
__global__ void k_prep(int* __restrict__ gcur, const int* __restrict__ gcnt,
                       float* __restrict__ inv_gcnt, float* __restrict__ out,
                       const float* __restrict__ b_pred,
                       const float* __restrict__ Wn, unsigned short* __restrict__ Wnt,
                       const float* __restrict__ We, unsigned short* __restrict__ Wet,
                       const float* __restrict__ W_ro, const float* __restrict__ W_pred,
                       float* __restrict__ wcv) {
  int bi = blockIdx.x, t = threadIdx.x;
  if (bi == 0) {
    gcur[t] = t * CAP;
  } else if (bi < 1 + NG / 256) {
    int g = (bi - 1) * 256 + t;
    inv_gcnt[g] = 1.0f / fmaxf((float)gcnt[g], 1.0f);
    out[g] = b_pred[0];
  } else if (bi < 1 + NG / 256 + 512) {
    int i = (bi - 1 - NG / 256) * 256 + t;        // L*256*128 total
    int l = i >> 15, k = (i >> 7) & 255, c = i & 127;
    Wnt[((size_t)l * HD + c) * 256 + k] = f2b(Wn[((size_t)l * 256 + k) * HD + c]);
  } else if (bi < 1 + NG / 256 + 512 + 16) {
    int i = (bi - 1 - NG / 256 - 512) * 256 + t;  // 128*32 total
    int col = i >> 5, k = i & 31;
    Wet[i] = (k < NA) ? f2b(We[(size_t)k * HD + col]) : (unsigned short)0;
  } else {
    if (t < 128) {
      float a = 0.f;
      for (int j = 0; j < HD; j++) a += W_ro[t * HD + j] * W_pred[j];
      wcv[t] = a;
    }
  }
}

// ---------------- bin edges into NB buckets by dst>>BSH ----------------
// packed = (dst&511)<<17 | src
__global__ __launch_bounds__(256) void k_bin(const int* __restrict__ src,
                                             const int* __restrict__ dst,
                                             int* __restrict__ gcur,
                                             uint* __restrict__ ebuf) {
  __shared__ int cnt[NB];
  __shared__ int gbase[NB];
  int t = threadIdx.x;
  cnt[t] = 0;
  int es[16], ed[16];
  int base = blockIdx.x * 4096 + t;
#pragma unroll
  for (int j = 0; j < 16; j++) {
    es[j] = src[base + j * 256];
    ed[j] = dst[base + j * 256];
  }
  __syncthreads();
#pragma unroll
  for (int j = 0; j < 16; j++) atomicAdd(&cnt[ed[j] >> BSH], 1);
  __syncthreads();
  int c = cnt[t];
  if (c > 0) gbase[t] = atomicAdd(&gcur[t], c);
  cnt[t] = 0;
  __syncthreads();
#pragma unroll
  for (int j = 0; j < 16; j++) {
    int b = ed[j] >> BSH;
    int r = atomicAdd(&cnt[b], 1);
    ebuf[(size_t)gbase[b] + r] = ((uint)(ed[j] & (BNOD - 1)) << 17) | (uint)es[j];
  }
}

// ---------------- fused CSR: hist + scans + row_start/deg/inv_deg + place ------
// one block per bucket; esrc laid out bucket-major (transparent via row_start).
__global__ __launch_bounds__(256) void k_csr(const int* __restrict__ gcur,
                                             const uint* __restrict__ ebuf,
                                             int* __restrict__ deg,
                                             int* __restrict__ row_start,
                                             float* __restrict__ inv_deg,
                                             int* __restrict__ esrc) {
  __shared__ int h[BNOD];      // histogram, later cursors
  __shared__ int ps[NB];       // pair-sum scan
  __shared__ int bs[NB];       // bucket-size scan
  int b = blockIdx.x, t = threadIdx.x;

  bs[t] = gcur[t] - t * CAP;   // bucket sizes
  h[t] = 0; h[t + 256] = 0;
  __syncthreads();
  for (int o = 1; o < 256; o <<= 1) {         // inclusive scan of bucket sizes
    int v = (t >= o) ? bs[t - o] : 0;
    __syncthreads();
    bs[t] += v;
    __syncthreads();
  }
  int boff = (b == 0) ? 0 : bs[b - 1];
  int n = gcur[b] - b * CAP;

  const uint* eb = ebuf + (size_t)b * CAP;
  for (int i = t; i < n; i += 256) atomicAdd(&h[eb[i] >> 17], 1);
  __syncthreads();

  int d0 = h[2 * t], d1 = h[2 * t + 1];
  ps[t] = d0 + d1;
  __syncthreads();
  for (int o = 1; o < 256; o <<= 1) {         // inclusive scan of node pairs
    int v = (t >= o) ? ps[t - o] : 0;
    __syncthreads();
    ps[t] += v;
    __syncthreads();
  }
  int excl = ps[t] - (d0 + d1);
  int r0 = boff + excl, r1 = r0 + d0;
  int v0 = b * BNOD + 2 * t;
  deg[v0] = d0;  deg[v0 + 1] = d1;
  row_start[v0] = r0;  row_start[v0 + 1] = r1;
  inv_deg[v0]     = 1.0f / fmaxf((float)d0, 1.0f);
  inv_deg[v0 + 1] = 1.0f / fmaxf((float)d1, 1.0f);
  __syncthreads();
  h[2 * t] = r0;  h[2 * t + 1] = r1;          // cursors
  __syncthreads();
  for (int i = t; i < n; i += 256) {
    uint p = eb[i];
    int r = atomicAdd(&h[p >> 17], 1);
    esrc[r] = (int)(p & 0x1FFFFu);
  }
}

// ---------------- embedding (MFMA): Xb = bf16(h @ W_emb) ----------------
// block: 64 rows x 128 cols, 4 waves 2x2; K=32 (padded from 28)
__global__ __launch_bounds__(256) void k_embed(const float* __restrict__ h,
                                               const unsigned short* __restrict__ Wet,
                                               unsigned short* __restrict__ Xb) {
  int t = threadIdx.x;
  int lane = t & 63, w = t >> 6;
  int wr = w >> 1, wc = w & 1;
  int row0 = blockIdx.x * 64 + wr * 32;
  int col0 = wc * 64;
  int fr = lane & 15;
  int fk = (lane >> 4) * 8;

  f32x4 acc[2][4] = {};
  bf16x8 a[2];
#pragma unroll
  for (int rt = 0; rt < 2; rt++) {
    int row = row0 + rt * 16 + fr;
    const float* hp = h + (size_t)row * NA + fk;
    float4 p = *(const float4*)hp;                    // k = fk..fk+3 (always < 28)
    float4 q = make_float4(0.f, 0.f, 0.f, 0.f);
    if (fk < 24) q = *(const float4*)(hp + 4);        // k = fk+4..fk+7; fk==24 -> pad 0
    a[rt][0] = (short)f2b(p.x); a[rt][1] = (short)f2b(p.y);
    a[rt][2] = (short)f2b(p.z); a[rt][3] = (short)f2b(p.w);
    a[rt][4] = (short)f2b(q.x); a[rt][5] = (short)f2b(q.y);
    a[rt][6] = (short)f2b(q.z); a[rt][7] = (short)f2b(q.w);
  }
#pragma unroll
  for (int ct = 0; ct < 4; ct++) {
    int col = col0 + ct * 16 + fr;
    bf16x8 b = *(const bf16x8*)(Wet + (size_t)col * 32 + fk);
#pragma unroll
    for (int rt = 0; rt < 2; rt++)
      acc[rt][ct] = __builtin_amdgcn_mfma_f32_16x16x32_bf16(a[rt], b, acc[rt][ct], 0, 0, 0);
  }
  int oc = lane & 15, orb = (lane >> 4) * 4;
#pragma unroll
  for (int rt = 0; rt < 2; rt++) {
#pragma unroll
    for (int ct = 0; ct < 4; ct++) {
      int col = col0 + ct * 16 + oc;
#pragma unroll
      for (int r = 0; r < 4; r++) {
        int row = row0 + rt * 16 + orb + r;
        Xb[(size_t)row * HD + col] = f2b(acc[rt][ct][r]);
      }
    }
  }
}

// ---------------- dual GEMM (MFMA, swapped operands): ----------------
// Qb = bf16(Hb @ W1 + bias), Pb8 = fp8(Hb @ W2); W = [W1; W2] (256 x 128).
// wave = 32 nodes (2 A-frag tiles, B reused x2) x 64 cols; block = 64 nodes x 128.
__global__ __launch_bounds__(256) void k_pq(const unsigned short* __restrict__ Hb,
                                            uint* __restrict__ Pb8,
                                            unsigned short* __restrict__ Qb,
                                            const unsigned short* __restrict__ Wt,
                                            const float* __restrict__ bias) {
  int t = threadIdx.x;
  int lane = t & 63, w = t >> 6;
  int ng = w >> 1, cg = w & 1;
  int fr = lane & 15, fkg = lane >> 4;
  int n0 = blockIdx.x * 64 + ng * 32;

  f32x4 accQ[2][4] = {}, accP[2][4] = {};
#pragma unroll
  for (int ks = 0; ks < 4; ks++) {
    bf16x8 aH[2];
#pragma unroll
    for (int nt = 0; nt < 2; nt++)
      aH[nt] = *(const bf16x8*)(Hb + (size_t)(n0 + nt * 16 + fr) * HD + ks * 32 + fkg * 8);
#pragma unroll
    for (int ct = 0; ct < 4; ct++) {
      const unsigned short* wrow =
          Wt + (size_t)(cg * 64 + ct * 16 + fr) * 256 + ks * 32 + fkg * 8;
      bf16x8 b1 = *(const bf16x8*)wrow;           // W1: k in [0,128)
      bf16x8 b2 = *(const bf16x8*)(wrow + 128);   // W2: k in [128,256)
#pragma unroll
      for (int nt = 0; nt < 2; nt++) {
        accQ[nt][ct] = __builtin_amdgcn_mfma_f32_16x16x32_bf16(b1, aH[nt], accQ[nt][ct], 0, 0, 0);
        accP[nt][ct] = __builtin_amdgcn_mfma_f32_16x16x32_bf16(b2, aH[nt], accP[nt][ct], 0, 0, 0);
      }
    }
  }
  // epilogue: lane -> node = n0+nt*16+fr, channels c0..c0+3
#pragma unroll
  for (int nt = 0; nt < 2; nt++) {
    int node = n0 + nt * 16 + fr;
#pragma unroll
    for (int ct = 0; ct < 4; ct++) {
      int c0 = cg * 64 + ct * 16 + fkg * 4;
      float4 bv = *(const float4*)(bias + c0);
      uint2 q;
      q.x = pack2(accQ[nt][ct][0] + bv.x, accQ[nt][ct][1] + bv.y);
      q.y = pack2(accQ[nt][ct][2] + bv.z, accQ[nt][ct][3] + bv.w);
      *(uint2*)(Qb + (size_t)node * HD + c0) = q;
      Pb8[(size_t)node * 32 + (c0 >> 2)] =
          pk_fp8x4(accP[nt][ct][0], accP[nt][ct][1], accP[nt][ct][2], accP[nt][ct][3]);
    }
  }
}

// ---------------- gather (fp8 P) + layer epilogue, v4 ----------------
// one wave per node; lane = (eg = lane>>4: edge slot, cl = lane&15: uint2 col).
// v4: 16-edge leading batch (4 loads in flight) covers the common d~16 case;
// Q/Hres/snorm/inv_deg hoisted; indices preloaded coalesced + shfl broadcast.
__global__ __launch_bounds__(256) void k_gapply(const uint2* __restrict__ Pg,
                      const uint4* __restrict__ Qg, const uint4* __restrict__ Hres,
                      uint4* __restrict__ Og,
                      const int* __restrict__ row_start, const int* __restrict__ deg,
                      const int* __restrict__ esrc, const float* __restrict__ inv_deg,
                      const float* __restrict__ snorm,
                      const float* __restrict__ wcv, const int* __restrict__ gid,
                      const float* __restrict__ inv_gcnt, float* __restrict__ out,
                      int last) {
  int v = blockIdx.x * 4 + (threadIdx.x >> 6);
  int lane = threadIdx.x & 63;
  int eg = lane >> 4;                       // edge slot 0..3
  int cl = lane & 15;                       // uint2 col: fp8 cols 8cl..8cl+7
  int rs = __builtin_amdgcn_readfirstlane(row_start[v]);
  int d  = __builtin_amdgcn_readfirstlane(deg[v]);

  // ---- hoisted epilogue operands (latency hides under the gather) ----
  float id = inv_deg[v];
  float sn = snorm[v];
  uint4 q  = Qg[(size_t)v * 16 + cl];       // lanes 16+ replicate -> coalesced
  uint4 hr = Hres[(size_t)v * 16 + cl];

  // ---- coalesced index preload: all of this node's edges in one load ----
  int dcap = min(d, 64);
  int myidx = 0;
  if (lane < dcap) myidx = esrc[rs + lane];

  float a0 = 0.f, a1 = 0.f, a2 = 0.f, a3 = 0.f;
  float a4 = 0.f, a5 = 0.f, a6 = 0.f, a7 = 0.f;

#define ACCX(X)                                                             \
  { f32x2 p0 = __builtin_amdgcn_cvt_pk_f32_fp8((int)(X).x, false);          \
    f32x2 p1 = __builtin_amdgcn_cvt_pk_f32_fp8((int)(X).x, true);           \
    f32x2 p2 = __builtin_amdgcn_cvt_pk_f32_fp8((int)(X).y, false);          \
    f32x2 p3 = __builtin_amdgcn_cvt_pk_f32_fp8((int)(X).y, true);           \
    a0 += p0[0]; a1 += p0[1]; a2 += p1[0]; a3 += p1[1];                     \
    a4 += p2[0]; a5 += p2[1]; a6 += p3[0]; a7 += p3[1]; }

  int e = 0;
  for (; e + 16 <= dcap; e += 16) {         // 16 edges = 4 loads in flight
    int i0 = __shfl(myidx, e + eg, 64);
    int i1 = __shfl(myidx, e + 4 + eg, 64);
    int i2 = __shfl(myidx, e + 8 + eg, 64);
    int i3 = __shfl(myidx, e + 12 + eg, 64);
    uint2 x0 = Pg[(size_t)i0 * 16 + cl];
    uint2 x1 = Pg[(size_t)i1 * 16 + cl];
    uint2 x2 = Pg[(size_t)i2 * 16 + cl];
    uint2 x3 = Pg[(size_t)i3 * 16 + cl];
    ACCX(x0)
    ACCX(x1)
    ACCX(x2)
    ACCX(x3)
  }
  if (e + 8 <= dcap) {
    int i0 = __shfl(myidx, e + eg, 64);
    int i1 = __shfl(myidx, e + 4 + eg, 64);
    uint2 x0 = Pg[(size_t)i0 * 16 + cl];
    uint2 x1 = Pg[(size_t)i1 * 16 + cl];
    ACCX(x0)
    ACCX(x1)
    e += 8;
  }
  if (e + 4 <= dcap) {
    int i0 = __shfl(myidx, e + eg, 64);
    uint2 x = Pg[(size_t)i0 * 16 + cl];
    ACCX(x)
    e += 4;
  }
  if (e < dcap) {                           // masked tail (<4 edges)
    uint2 x = make_uint2(0u, 0u);
    if (e + eg < dcap) {
      int i0 = __shfl(myidx, e + eg, 64);
      x = Pg[(size_t)i0 * 16 + cl];
    }
    ACCX(x)
  }
  for (int ee = 64; ee < d; ee += 4) {      // d>64: essentially never (Poisson 16)
    uint2 x = make_uint2(0u, 0u);
    if (ee + eg < d) x = Pg[(size_t)esrc[rs + ee + eg] * 16 + cl];
    ACCX(x)
  }
#undef ACCX

  // reduce across the 4 edge slots
  a0 += __shfl_xor(a0, 16, 64);  a0 += __shfl_xor(a0, 32, 64);
  a1 += __shfl_xor(a1, 16, 64);  a1 += __shfl_xor(a1, 32, 64);
  a2 += __shfl_xor(a2, 16, 64);  a2 += __shfl_xor(a2, 32, 64);
  a3 += __shfl_xor(a3, 16, 64);  a3 += __shfl_xor(a3, 32, 64);
  a4 += __shfl_xor(a4, 16, 64);  a4 += __shfl_xor(a4, 32, 64);
  a5 += __shfl_xor(a5, 16, 64);  a5 += __shfl_xor(a5, 32, 64);
  a6 += __shfl_xor(a6, 16, 64);  a6 += __shfl_xor(a6, 32, 64);
  a7 += __shfl_xor(a7, 16, 64);  a7 += __shfl_xor(a7, 32, 64);

  if (eg == 0) {                            // lanes 0..15: full-row uint4 IO
    float o0 = fmaxf(blo(q.x) + a0 * id, 0.f) * sn + blo(hr.x);
    float o1 = fmaxf(bhi(q.x) + a1 * id, 0.f) * sn + bhi(hr.x);
    float o2 = fmaxf(blo(q.y) + a2 * id, 0.f) * sn + blo(hr.y);
    float o3 = fmaxf(bhi(q.y) + a3 * id, 0.f) * sn + bhi(hr.y);
    float o4 = fmaxf(blo(q.z) + a4 * id, 0.f) * sn + blo(hr.z);
    float o5 = fmaxf(bhi(q.z) + a5 * id, 0.f) * sn + bhi(hr.z);
    float o6 = fmaxf(blo(q.w) + a6 * id, 0.f) * sn + blo(hr.w);
    float o7 = fmaxf(bhi(q.w) + a7 * id, 0.f) * sn + bhi(hr.w);
    if (!last) {
      uint4 o;
      o.x = pack2(o0, o1);
      o.y = pack2(o2, o3);
      o.z = pack2(o4, o5);
      o.w = pack2(o6, o7);
      Og[(size_t)v * 16 + cl] = o;
    } else {
      float4 w0 = *(const float4*)(wcv + 8 * cl);
      float4 w1 = *(const float4*)(wcv + 8 * cl + 4);
      float p = o0 * w0.x + o1 * w0.y + o2 * w0.z + o3 * w0.w
              + o4 * w1.x + o5 * w1.y + o6 * w1.z + o7 * w1.w;
      p += __shfl_xor(p, 8, 64);
      p += __shfl_xor(p, 4, 64);
      p += __shfl_xor(p, 2, 64);
      p += __shfl_xor(p, 1, 64);
      if (cl == 0) {
        int g = gid[v];
        atomicAdd(&out[g], p * inv_gcnt[g]);
      }
    }
  }
}

// ---------------- launch ----------------
extern "C" void kernel_launch(void* const* d_in, const int* in_sizes, int n_in,
                              void* d_out, int out_size, void* d_ws, size_t ws_size,
                              hipStream_t stream) {
  const float* h      = (const float*)d_in[0];
  const float* snorm  = (const float*)d_in[1];
  const float* W_emb  = (const float*)d_in[2];
  const float* W_node = (const float*)d_in[3];
  const float* b_node = (const float*)d_in[4];
  const float* W_ro   = (const float*)d_in[5];
  const float* W_pred = (const float*)d_in[6];
  const float* b_pred = (const float*)d_in[7];
  const int*   src    = (const int*)d_in[8];
  const int*   dst    = (const int*)d_in[9];
  const int*   gid    = (const int*)d_in[10];
  float* out = (float*)d_out;

  char* ws = (char*)d_ws;
  unsigned short* Xb   = (unsigned short*)(ws + OFF_XB);
  unsigned short* Yb   = (unsigned short*)(ws + OFF_YB);
  uint*  Pb8      = (uint*)(ws + OFF_PB);
  int*   esrc     = (int*)(ws + OFF_ESRC);
  int*   deg      = (int*)(ws + OFF_DEG);
  int*   gcnt     = (int*)(ws + OFF_GCNT);
  int*   row_s    = (int*)(ws + OFF_ROW);
  float* inv_deg  = (float*)(ws + OFF_IDEG);
  float* inv_gcnt = (float*)(ws + OFF_IGC);
  float* wcv      = (float*)(ws + OFF_WC);
  unsigned short* Wnt = (unsigned short*)(ws + OFF_WNT);
  uint*  ebuf     = (uint*)(ws + OFF_EBUF);
  int*   gcur     = (int*)(ws + OFF_GCUR);
  unsigned short* Wet = (unsigned short*)(ws + OFF_WET);

  hipMemsetAsync(ws + OFF_GCNT, 0, (size_t)NG * 4, stream);

  k_ghist<<<NN / 256, 256, 0, stream>>>(gid, gcnt);
  k_prep<<<1 + NG / 256 + 512 + 16 + 1, 256, 0, stream>>>(
      gcur, gcnt, inv_gcnt, out, b_pred, W_node, Wnt, W_emb, Wet, W_ro, W_pred, wcv);
  k_bin<<<NE / 4096, 256, 0, stream>>>(src, dst, gcur, ebuf);
  k_csr<<<NB, 256, 0, stream>>>(gcur, ebuf, deg, row_s, inv_deg, esrc);

  k_embed<<<NN / 64, 256, 0, stream>>>(h, Wet, Xb);

  for (int l = 0; l < NL; l++) {
    unsigned short* hb = (l & 1) ? Yb : Xb;   // layer input
    unsigned short* qo = (l & 1) ? Xb : Yb;   // Q buffer, overwritten in-place by O
    k_pq<<<NN / 64, 256, 0, stream>>>(hb, Pb8, qo, Wnt + (size_t)l * HD * 256,
                                      b_node + (size_t)l * HD);
    k_gapply<<<NN / 4, 256, 0, stream>>>((const uint2*)Pb8, (const uint4*)qo,
                                         (const uint4*)hb, (uint4*)qo,
                                         row_s, deg, esrc, inv_deg, snorm,
                                         wcv, gid, inv_gcnt, out, (l == NL - 1) ? 1 : 0);
  }
}